// Round 8
// baseline (502.467 us; speedup 1.0000x reference)
//
#include <hip/hip_runtime.h>
#include <hip/hip_bf16.h>
#include <math.h>

#define BB 16
#define NN 512
#define DD 256
#define KK 12

typedef __bf16 bf16x8 __attribute__((ext_vector_type(8)));
typedef __bf16 bf16x4 __attribute__((ext_vector_type(4)));
typedef float  f32x4  __attribute__((ext_vector_type(4)));

// workspace layout (bytes)
#define WS_WM     0              // wm[b,n] = w*mask_n, f32, 32KB
#define WS_MASKBF 32768          // maskbf[b,n] bf16 0/1, 16KB
#define WS_NODEBF 49152          // node bf16 [B][N][D] (unscaled, self term), 4MB
#define WS_WKBF   8437760        // Wk bf16 [K][D][D], 1.5MB
#define WS_WSBF   10010624       // Ws bf16 [D][D], 128KB
#define WS_YT     10174464       // Yt bf16 [K][B][D][N] = 50.33MB (proven to fit: r7 ran)

// raw barrier: drain LDS only; vmcnt deliberately NOT drained so global
// prefetch loads stay in flight across the barrier.
#define BAR() do { \
    __builtin_amdgcn_sched_barrier(0); \
    asm volatile("s_waitcnt lgkmcnt(0)" ::: "memory"); \
    __builtin_amdgcn_s_barrier(); \
    __builtin_amdgcn_sched_barrier(0); \
} while (0)

// ---------------------------------------------------------------- k1: w, all_weight, wm, maskbf, node_bf16
__global__ __launch_bounds__(256) void k1_prep(const float* __restrict__ node,
        const float* __restrict__ Ww, const float* __restrict__ bw,
        const int* __restrict__ node_mask,
        float* __restrict__ wm, __bf16* __restrict__ maskbf,
        __bf16* __restrict__ node_bf, float* __restrict__ all_w) {
    int t = threadIdx.x;
    int lane = t & 63;
    int row = blockIdx.x * 4 + (t >> 6);           // b*N + n
    const float4 nv = *(const float4*)(node + (size_t)row * DD + lane * 4);
    const float4 wv = *(const float4*)(Ww + lane * 4);
    float dot = nv.x*wv.x + nv.y*wv.y + nv.z*wv.z + nv.w*wv.w;
    #pragma unroll
    for (int off = 32; off > 0; off >>= 1) dot += __shfl_xor(dot, off);
    float w = 1.0f / (1.0f + expf(-(dot + bw[0])));
    int mk = node_mask[row];
    if (lane == 0) {
        wm[row]     = w * (float)mk;
        all_w[row]  = w;
        maskbf[row] = (__bf16)(float)mk;
    }
    bf16x4 nb = {(__bf16)nv.x, (__bf16)nv.y, (__bf16)nv.z, (__bf16)nv.w};
    *(bf16x4*)(node_bf + (size_t)row * DD + lane * 4) = nb;
}

// ---------------------------------------------------------------- k1b: Wk, Ws -> bf16
__global__ __launch_bounds__(256) void k1b_convert(const float* __restrict__ Wk,
        const float* __restrict__ Ws, __bf16* __restrict__ Wk_bf, __bf16* __restrict__ Ws_bf) {
    const int KDD = KK * DD * DD;
    int idx = (blockIdx.x * 256 + threadIdx.x) * 4;
    if (idx < KDD) {
        float4 v = *(const float4*)(Wk + idx);
        bf16x4 o = {(__bf16)v.x, (__bf16)v.y, (__bf16)v.z, (__bf16)v.w};
        *(bf16x4*)(Wk_bf + idx) = o;
    } else {
        int j = idx - KDD;
        if (j < DD * DD) {
            float4 v = *(const float4*)(Ws + j);
            bf16x4 o = {(__bf16)v.x, (__bf16)v.y, (__bf16)v.z, (__bf16)v.w};
            *(bf16x4*)(Ws_bf + j) = o;
        }
    }
}

// ---------------------------------------------------------------- k3: Yt[k][b][d][n] = wm[b,n] * sum_e Wk[k,d,e] * node_bf[b,n,e]
// v2: OPERANDS SWAPPED vs r7 — mfma(A=node rows n, B=Wk rows d) gives D[n][d]
// with the 4 per-lane acc values at CONSECUTIVE n -> one bf16x4 (8B) store.
// 32 scalar 2B stores/thread (r7, ~65us VMEM-issue-bound) -> 8 packed stores.
__global__ __launch_bounds__(256) void k3_ygemm(const __bf16* __restrict__ node_bf,
        const __bf16* __restrict__ Wk_bf, const float* __restrict__ wm,
        __bf16* __restrict__ Yt) {
    int bx = blockIdx.x;
    int nt = bx & 15;
    int kb = bx >> 4;
    int b  = kb & 15;
    int k  = kb >> 4;
    int t = threadIdx.x;
    int lane = t & 63;
    int w = t >> 6;                   // wave 0..3
    int q = lane >> 4;
    int l16 = lane & 15;
    int wsub = w * 64;                // wave's 64 d-rows

    f32x4 acc[4][2];                  // [fd][fn]; D rows = n, cols = d
    #pragma unroll
    for (int i = 0; i < 4; i++)
        #pragma unroll
        for (int j = 0; j < 2; j++) acc[i][j] = (f32x4){0.f, 0.f, 0.f, 0.f};

    #pragma unroll
    for (int ec = 0; ec < 8; ec++) {
        int e0 = ec * 32;
        bf16x8 aW[4], bN[2];
        #pragma unroll
        for (int fd = 0; fd < 4; fd++)
            aW[fd] = *(const bf16x8*)(Wk_bf +
                ((size_t)(k * DD + wsub + fd * 16 + l16)) * DD + e0 + q * 8);
        #pragma unroll
        for (int fn = 0; fn < 2; fn++)
            bN[fn] = *(const bf16x8*)(node_bf +
                ((size_t)(b * NN + nt * 32 + fn * 16 + l16)) * DD + e0 + q * 8);
        #pragma unroll
        for (int fd = 0; fd < 4; fd++)
            #pragma unroll
            for (int fn = 0; fn < 2; fn++)
                acc[fd][fn] = __builtin_amdgcn_mfma_f32_16x16x32_bf16(
                    bN[fn], aW[fd], acc[fd][fn], 0, 0, 0);   // A=node(n), B=Wk(d)
    }

    // D layout: col=l16 -> d-frag row; row=q*4+r -> n-frag row (consecutive n!)
    float4 wmv[2];
    #pragma unroll
    for (int fn = 0; fn < 2; fn++)
        wmv[fn] = *(const float4*)(wm + b * NN + nt * 32 + fn * 16 + q * 4);

    #pragma unroll
    for (int fd = 0; fd < 4; fd++)
        #pragma unroll
        for (int fn = 0; fn < 2; fn++) {
            int d = wsub + fd * 16 + l16;
            int n = nt * 32 + fn * 16 + q * 4;
            bf16x4 o = {(__bf16)(acc[fd][fn][0] * wmv[fn].x),
                        (__bf16)(acc[fd][fn][1] * wmv[fn].y),
                        (__bf16)(acc[fd][fn][2] * wmv[fn].z),
                        (__bf16)(acc[fd][fn][3] * wmv[fn].w)};
            *(bf16x4*)(Yt + ((size_t)(k * BB + b) * DD + d) * NN + n) = o;
        }
}

// ---------------------------------------------------------------- k45_yt: agg GEMM over concatenated (k,n)
// v2: 16-row m-tiles, grid 512 -> 2 blocks/CU. In the Yt factorization the
// B-operand (Yt) is b-shared and XCD-L2-local (512KB/k working set), so the
// m-split adds NO HBM traffic (unlike r1's node_t/Wk duplication) while doubling
// the waves available to hide Yt's L2 latency (r7's limiter: VGPR=64, loads
// issued just-in-time, 1 block/CU). byt loads batched 4-kk-per-group (8 in flight).
__global__ __launch_bounds__(512, 4) void k45_yt(const int* __restrict__ graphs,
        const int* __restrict__ node_mask, const __bf16* __restrict__ maskbf,
        const __bf16* __restrict__ Yt, const __bf16* __restrict__ node_bf,
        const __bf16* __restrict__ Ws_bf,
        const float* __restrict__ bs, float* __restrict__ out) {
    __shared__ __align__(16) __bf16 Abf[2][16][520]; // 33.3 KB adjacency dbuf
    __shared__ float cntp[8][16];
    __shared__ float sm[16];
    int bx = blockIdx.x;
    int b  = (bx & 7) + 8 * ((bx >> 3) & 1);        // XCD-local b
    int mt = bx >> 4;                                // 0..31
    int m0 = mt * 16;
    int t = threadIdx.x;
    int lane = t & 63;
    int w = t >> 6;                                  // wave 0..7
    int q = lane >> 4;
    int l16 = lane & 15;
    int dsub = w * 32;                               // wave's d-range

    int crow = t >> 7;                               // convert: row parity 0..3
    int ccol = (t & 127) * 4;                        // convert: int32-column base

    bf16x8 bfm[2];
    #pragma unroll
    for (int c = 0; c < 2; c++) {
        bfm[c] = (bf16x8){0,0,0,0,0,0,0,0};
        if (l16 == 0)
            bfm[c] = *(const bf16x8*)(maskbf + b * NN + (w * 2 + c) * 32 + q * 8);
    }

    f32x4 accO[2];                                   // [fd], fm=1 (16 rows)
    accO[0] = (f32x4){0.f, 0.f, 0.f, 0.f};
    accO[1] = (f32x4){0.f, 0.f, 0.f, 0.f};
    f32x4 accC = (f32x4){0.f, 0.f, 0.f, 0.f};

    int4 g[4];

#define LOADG(kk_) do { \
        const int4* gb = (const int4*)(graphs + ((size_t)(((kk_) * BB + b) * NN + m0)) * NN); \
        _Pragma("unroll") \
        for (int u = 0; u < 4; u++) g[u] = gb[u * 512 + t]; \
    } while (0)

#define CONVERT(nb_) do { \
        _Pragma("unroll") \
        for (int u = 0; u < 4; u++) { \
            int row = u * 4 + crow; \
            unsigned p0 = (unsigned)g[u].x | ((unsigned)g[u].y << 16); \
            unsigned p1 = (unsigned)g[u].z | ((unsigned)g[u].w << 16); \
            unsigned drel = (unsigned)(m0 + row - ccol); \
            if (drel < 2u)      p0 &= ~(0xFFFFu << (16 * drel)); \
            else if (drel < 4u) p1 &= ~(0xFFFFu << (16 * (drel - 2))); \
            uint2 st; st.x = p0 * 0x3F80u; st.y = p1 * 0x3F80u; \
            *(uint2*)&Abf[nb_][row][ccol] = st; \
        } \
    } while (0)

    LOADG(0);
    CONVERT(0);
    LOADG(1);
    BAR();

    int ac = 0;

    #pragma unroll 1
    for (int k = 0; k < KK; k++) {
        const __bf16* ytk = Yt + ((size_t)(k * BB + b) * DD + dsub) * NN;
        // 4 groups of 4 kk: 8 byt loads issued per group before any consuming MFMA
        #pragma unroll
        for (int gg = 0; gg < 4; gg++) {
            bf16x8 byt4[4][2], af4[4];
            #pragma unroll
            for (int j = 0; j < 4; j++) {
                int n0c = (gg * 4 + j) * 32;
                #pragma unroll
                for (int fd = 0; fd < 2; fd++)
                    byt4[j][fd] = *(const bf16x8*)(ytk +
                        (size_t)(fd * 16 + l16) * NN + n0c + q * 8);
            }
            #pragma unroll
            for (int j = 0; j < 4; j++)
                af4[j] = *(const bf16x8*)&Abf[ac][l16][(gg * 4 + j) * 32 + q * 8];
            #pragma unroll
            for (int j = 0; j < 4; j++) {
                int kk = gg * 4 + j;
                #pragma unroll
                for (int fd = 0; fd < 2; fd++)
                    accO[fd] = __builtin_amdgcn_mfma_f32_16x16x32_bf16(
                        af4[j], byt4[j][fd], accO[fd], 0, 0, 0);
                if ((kk >> 1) == w)
                    accC = __builtin_amdgcn_mfma_f32_16x16x32_bf16(
                        af4[j], bfm[kk & 1], accC, 0, 0, 0);
            }
        }

        if (k < KK - 1) CONVERT(ac ^ 1);
        if (k < KK - 2) LOADG(k + 2);

        BAR();
        ac ^= 1;
    }

    // counts: block-local reduce, s[m] = mask_m / max(1, cnt)
    if (l16 == 0) {
        #pragma unroll
        for (int r = 0; r < 4; r++)
            cntp[w][q * 4 + r] = accC[r];
    }
    __syncthreads();
    if (t < 16) {
        float c = 0.0f;
        #pragma unroll
        for (int w8 = 0; w8 < 8; w8++) c += cntp[w8][t];
        int mk = node_mask[b * NN + m0 + t];
        sm[t] = (float)mk / (c >= 0.5f ? c : 1.0f);
    }
    __syncthreads();

    #pragma unroll
    for (int r = 0; r < 4; r++) {
        float s = sm[q * 4 + r];
        accO[0][r] *= s;
        accO[1][r] *= s;
    }

    // self: accO += node @ Ws^T
    #pragma unroll
    for (int ee = 0; ee < 8; ee++) {
        int e0c = ee * 32;
        bf16x8 afS = *(const bf16x8*)(node_bf +
            ((size_t)(b * NN + m0 + l16)) * DD + e0c + q * 8);
        bf16x8 bwS[2];
        #pragma unroll
        for (int fd = 0; fd < 2; fd++)
            bwS[fd] = *(const bf16x8*)(Ws_bf +
                ((size_t)(dsub + fd * 16 + l16)) * DD + e0c + q * 8);
        #pragma unroll
        for (int fd = 0; fd < 2; fd++)
            accO[fd] = __builtin_amdgcn_mfma_f32_16x16x32_bf16(
                afS, bwS[fd], accO[fd], 0, 0, 0);
    }

    // epilogue: + bs, relu, store f32
    #pragma unroll
    for (int fd = 0; fd < 2; fd++) {
        int d = dsub + fd * 16 + l16;
        float bsv = bs[d];
        #pragma unroll
        for (int r = 0; r < 4; r++) {
            int m = m0 + q * 4 + r;
            float v = accO[fd][r] + bsv;
            out[((size_t)(b * NN + m)) * DD + d] = fmaxf(v, 0.0f);
        }
    }
#undef LOADG
#undef CONVERT
}

// ----------------------------------------------------------------
extern "C" void kernel_launch(void* const* d_in, const int* in_sizes, int n_in,
                              void* d_out, int out_size, void* d_ws, size_t ws_size,
                              hipStream_t stream) {
    const float* node      = (const float*)d_in[0];
    const float* Ww        = (const float*)d_in[1];
    const float* bw        = (const float*)d_in[2];
    const float* Ws        = (const float*)d_in[3];
    const float* bs        = (const float*)d_in[4];
    const float* Wk        = (const float*)d_in[5];
    const int*   node_mask = (const int*)d_in[6];
    const int*   graphs    = (const int*)d_in[7];
    float* out   = (float*)d_out;
    float* all_w = out + (size_t)BB * NN * DD;

    char* ws = (char*)d_ws;
    float*  wm      = (float*)(ws + WS_WM);
    __bf16* maskbf  = (__bf16*)(ws + WS_MASKBF);
    __bf16* node_bf = (__bf16*)(ws + WS_NODEBF);
    __bf16* Wk_bf   = (__bf16*)(ws + WS_WKBF);
    __bf16* Ws_bf   = (__bf16*)(ws + WS_WSBF);
    __bf16* Yt      = (__bf16*)(ws + WS_YT);

    k1_prep    <<<2048, 256, 0, stream>>>(node, Ww, bw, node_mask, wm, maskbf, node_bf, all_w);
    k1b_convert<<< 832, 256, 0, stream>>>(Wk, Ws, Wk_bf, Ws_bf);
    k3_ygemm   <<<3072, 256, 0, stream>>>(node_bf, Wk_bf, wm, Yt);
    k45_yt     <<< 512, 512, 0, stream>>>(graphs, node_mask, maskbf, Yt, node_bf,
                                          Ws_bf, bs, out);
}

// Round 9
// 482.835 us; speedup vs baseline: 1.0407x; 1.0407x over previous
//
#include <hip/hip_runtime.h>
#include <hip/hip_bf16.h>
#include <math.h>

#define BB 16
#define NN 512
#define DD 256
#define KK 12

typedef __bf16 bf16x8 __attribute__((ext_vector_type(8)));
typedef __bf16 bf16x4 __attribute__((ext_vector_type(4)));
typedef float  f32x4  __attribute__((ext_vector_type(4)));

// workspace layout (bytes)
#define WS_WM     0              // wm[b,n] = w*mask_n, f32, 32KB
#define WS_MASKBF 32768          // maskbf[b,n] bf16 0/1, 16KB
#define WS_NODEBF 49152          // node bf16 [B][N][D] (unscaled, self term), 4MB
#define WS_NODET  4243456        // node_t bf16 [B][D][N], scaled by wm, 4MB
#define WS_WKBF   8437760        // Wk bf16 [K][D][D], 1.5MB
#define WS_WSBF   10010624       // Ws bf16 [D][D], 128KB

// raw barrier: drain LDS only; vmcnt deliberately NOT drained so global
// prefetch loads stay in flight across the barrier.
#define BAR() do { \
    __builtin_amdgcn_sched_barrier(0); \
    asm volatile("s_waitcnt lgkmcnt(0)" ::: "memory"); \
    __builtin_amdgcn_s_barrier(); \
    __builtin_amdgcn_sched_barrier(0); \
} while (0)

// ---------------------------------------------------------------- k1: w, all_weight, wm, maskbf, node_bf16
__global__ __launch_bounds__(256) void k1_prep(const float* __restrict__ node,
        const float* __restrict__ Ww, const float* __restrict__ bw,
        const int* __restrict__ node_mask,
        float* __restrict__ wm, __bf16* __restrict__ maskbf,
        __bf16* __restrict__ node_bf, float* __restrict__ all_w) {
    int t = threadIdx.x;
    int lane = t & 63;
    int row = blockIdx.x * 4 + (t >> 6);           // b*N + n
    const float4 nv = *(const float4*)(node + (size_t)row * DD + lane * 4);
    const float4 wv = *(const float4*)(Ww + lane * 4);
    float dot = nv.x*wv.x + nv.y*wv.y + nv.z*wv.z + nv.w*wv.w;
    #pragma unroll
    for (int off = 32; off > 0; off >>= 1) dot += __shfl_xor(dot, off);
    float w = 1.0f / (1.0f + expf(-(dot + bw[0])));
    int mk = node_mask[row];
    if (lane == 0) {
        wm[row]     = w * (float)mk;
        all_w[row]  = w;
        maskbf[row] = (__bf16)(float)mk;
    }
    bf16x4 nb = {(__bf16)nv.x, (__bf16)nv.y, (__bf16)nv.z, (__bf16)nv.w};
    *(bf16x4*)(node_bf + (size_t)row * DD + lane * 4) = nb;
}

// ---------------------------------------------------------------- k1b: Wk, Ws -> bf16
__global__ __launch_bounds__(256) void k1b_convert(const float* __restrict__ Wk,
        const float* __restrict__ Ws, __bf16* __restrict__ Wk_bf, __bf16* __restrict__ Ws_bf) {
    const int KDD = KK * DD * DD;
    int idx = (blockIdx.x * 256 + threadIdx.x) * 4;
    if (idx < KDD) {
        float4 v = *(const float4*)(Wk + idx);
        bf16x4 o = {(__bf16)v.x, (__bf16)v.y, (__bf16)v.z, (__bf16)v.w};
        *(bf16x4*)(Wk_bf + idx) = o;
    } else {
        int j = idx - KDD;
        if (j < DD * DD) {
            float4 v = *(const float4*)(Ws + j);
            bf16x4 o = {(__bf16)v.x, (__bf16)v.y, (__bf16)v.z, (__bf16)v.w};
            *(bf16x4*)(Ws_bf + j) = o;
        }
    }
}

// ---------------------------------------------------------------- k2: node fp32 [B][N][D] -> node_t bf16 [B][D][N] scaled by wm[b,n]
__global__ __launch_bounds__(256) void k2_transpose(const float* __restrict__ node,
        const float* __restrict__ wm, __bf16* __restrict__ dst) {
    __shared__ float tile[64][65];
    int bx = blockIdx.x;
    int b = bx >> 5; int rest = bx & 31; int nt = rest >> 2; int dt = rest & 3;
    int n0 = nt * 64, d0 = dt * 64;
    int t = threadIdx.x;
    #pragma unroll
    for (int i = 0; i < 16; i++) {
        int idx = i * 256 + t;
        int n = idx >> 6, d = idx & 63;
        tile[n][d] = node[((size_t)(b * NN + n0 + n)) * DD + d0 + d];
    }
    __syncthreads();
    #pragma unroll
    for (int i = 0; i < 16; i++) {
        int idx = i * 256 + t;
        int d = idx >> 6, n = idx & 63;
        float w = wm[b * NN + n0 + n];
        dst[((size_t)(b * DD + d0 + d)) * NN + n0 + n] = (__bf16)(tile[n][d] * w);
    }
}

// ---------------------------------------------------------------- k45: fused stageA+stageB
// r4 variant with LDS dieted to 67 KB for 2 blocks/CU: Abf SINGLE-buffered
// (back to r0's 2-barrier schedule), Tk double-buffered. Per-block work,
// loads, MFMA count and HBM traffic are BIT-IDENTICAL to r4 (128us @ 1 blk/CU)
// -- this isolates the occupancy variable that r1/r3/r8 confounded with
// traffic increases. 2 co-resident blocks overlap each other's barrier
// drains, LDS issue, and L2 latency.
__global__ __launch_bounds__(512, 4) void k45_fused(const int* __restrict__ graphs,
        const int* __restrict__ node_mask, const __bf16* __restrict__ maskbf,
        const __bf16* __restrict__ node_t, const __bf16* __restrict__ node_bf,
        const __bf16* __restrict__ Wk_bf, const __bf16* __restrict__ Ws_bf,
        const float* __restrict__ bs, float* __restrict__ out) {
    __shared__ __align__(16) __bf16 Abf[32][520];    // 33.3 KB adjacency (single)
    __shared__ __align__(16) __bf16 Tk[2][32][264];  // 33.8 KB T-tile dbuf
    __shared__ float cntp[8][32];
    __shared__ float sm[32];
    int bx = blockIdx.x;
    int b  = (bx & 7) + 8 * ((bx >> 3) & 1);        // XCD-local b: each XCD sees b=x, x+8
    int mt = bx >> 4;
    int m0 = mt * 32;
    int t = threadIdx.x;
    int lane = t & 63;
    int w = t >> 6;                                  // wave 0..7
    int q = lane >> 4;
    int l16 = lane & 15;
    int esub = w * 32;                               // wave's e-range in stage A
    int dsub = w * 32;                               // wave's d-range in stage B

    int crow = t >> 7;                               // convert: row parity 0..3
    int ccol = (t & 127) * 4;                        // convert: int32-column base

    f32x4 accO[2][2];
    #pragma unroll
    for (int i = 0; i < 2; i++)
        #pragma unroll
        for (int j = 0; j < 2; j++) accO[i][j] = (f32x4){0.f, 0.f, 0.f, 0.f};
    f32x4 accC[2];
    accC[0] = (f32x4){0.f, 0.f, 0.f, 0.f};
    accC[1] = (f32x4){0.f, 0.f, 0.f, 0.f};

    int4 g[8];

#define LOADG(kk_) do { \
        const int4* gb = (const int4*)(graphs + ((size_t)(((kk_) * BB + b) * NN + m0)) * NN); \
        _Pragma("unroll") \
        for (int u = 0; u < 8; u++) g[u] = gb[u * 512 + t]; \
    } while (0)

#define CONVERT() do { \
        _Pragma("unroll") \
        for (int u = 0; u < 8; u++) { \
            int row = u * 4 + crow; \
            unsigned p0 = (unsigned)g[u].x | ((unsigned)g[u].y << 16); \
            unsigned p1 = (unsigned)g[u].z | ((unsigned)g[u].w << 16); \
            unsigned drel = (unsigned)(m0 + row - ccol); \
            if (drel < 2u)      p0 &= ~(0xFFFFu << (16 * drel)); \
            else if (drel < 4u) p1 &= ~(0xFFFFu << (16 * (drel - 2))); \
            uint2 st; st.x = p0 * 0x3F80u; st.y = p1 * 0x3F80u; \
            *(uint2*)&Abf[row][ccol] = st; \
        } \
    } while (0)

    // prologue: strip 0 -> regs -> Abf; issue strip 1; barrier (Abf ready)
    LOADG(0);
    CONVERT();
    LOADG(1);
    BAR();

    int tc = 0;

    #pragma unroll 1
    for (int k = 0; k < KK; k++) {
        // ---- stage A: T_k[m, e-sub] = sum_n A[m,n] * wnode[n,e], reading Abf
        f32x4 accT[2][2];
        #pragma unroll
        for (int i = 0; i < 2; i++)
            #pragma unroll
            for (int jj = 0; jj < 2; jj++) accT[i][jj] = (f32x4){0.f, 0.f, 0.f, 0.f};
        #pragma unroll
        for (int kk = 0; kk < 16; kk++) {
            int n0c = kk * 32;
            bf16x8 af[2], bfr[2];
            #pragma unroll
            for (int fm = 0; fm < 2; fm++)
                af[fm] = *(const bf16x8*)&Abf[fm * 16 + l16][n0c + q * 8];
            #pragma unroll
            for (int fd = 0; fd < 2; fd++)
                bfr[fd] = *(const bf16x8*)(node_t +
                    ((size_t)(b * DD + esub + fd * 16 + l16)) * NN + n0c + q * 8);
            #pragma unroll
            for (int fm = 0; fm < 2; fm++)
                #pragma unroll
                for (int fd = 0; fd < 2; fd++)
                    accT[fm][fd] = __builtin_amdgcn_mfma_f32_16x16x32_bf16(
                        af[fm], bfr[fd], accT[fm][fd], 0, 0, 0);
            // count MFMA: wave w covers chunks {2w, 2w+1}; col0 of D = sum_n A[m,n]*mask[n]
            if ((kk >> 1) == w) {
                bf16x8 bfm = (bf16x8){0,0,0,0,0,0,0,0};
                if (l16 == 0)
                    bfm = *(const bf16x8*)(maskbf + b * NN + n0c + q * 8);
                accC[0] = __builtin_amdgcn_mfma_f32_16x16x32_bf16(af[0], bfm, accC[0], 0, 0, 0);
                accC[1] = __builtin_amdgcn_mfma_f32_16x16x32_bf16(af[1], bfm, accC[1], 0, 0, 0);
            }
        }

        // ---- T_k -> LDS bf16 (C/D layout: col=l16, row=q*4+r); Tk[tc^1] was
        // last read by stage B(k-1)? No: stage A(k) writes Tk[tc]; stage B(k-2)
        // read Tk[tc] two barriers ago -> safe.
        #pragma unroll
        for (int fm = 0; fm < 2; fm++)
            #pragma unroll
            for (int fd = 0; fd < 2; fd++) {
                int col = esub + fd * 16 + l16;
                #pragma unroll
                for (int r = 0; r < 4; r++)
                    Tk[tc][fm * 16 + q * 4 + r][col] = (__bf16)accT[fm][fd][r];
            }

        BAR();                                       // Abf reads + Tk[tc] writes drained

        // ---- convert strip k+1 into Abf (safe now); issue strip k+2 loads
        if (k < KK - 1) CONVERT();
        if (k < KK - 2) LOADG(k + 2);

        // ---- stage B: accO[m, d-sub] += sum_e T_k[m,e] * Wk[k,d,e]
        #pragma unroll
        for (int ee = 0; ee < 8; ee++) {
            int e0c = ee * 32;
            bf16x8 afT[2], bw2[2];
            #pragma unroll
            for (int fm = 0; fm < 2; fm++)
                afT[fm] = *(const bf16x8*)&Tk[tc][fm * 16 + l16][e0c + q * 8];
            #pragma unroll
            for (int fd = 0; fd < 2; fd++)
                bw2[fd] = *(const bf16x8*)(Wk_bf +
                    ((size_t)(k * DD + dsub + fd * 16 + l16)) * DD + e0c + q * 8);
            #pragma unroll
            for (int fm = 0; fm < 2; fm++)
                #pragma unroll
                for (int fd = 0; fd < 2; fd++)
                    accO[fm][fd] = __builtin_amdgcn_mfma_f32_16x16x32_bf16(
                        afT[fm], bw2[fd], accO[fm][fd], 0, 0, 0);
        }

        BAR();                                       // CONVERT writes drained for stage A(k+1);
                                                     // Tk[tc] reads drained (overwritten at k+2)
        tc ^= 1;
    }

    // ---- counts: block-local reduce, s[m] = mask_m / max(1, cnt)
    if (l16 == 0) {
        #pragma unroll
        for (int fm = 0; fm < 2; fm++)
            #pragma unroll
            for (int r = 0; r < 4; r++)
                cntp[w][fm * 16 + q * 4 + r] = accC[fm][r];
    }
    __syncthreads();
    if (t < 32) {
        float c = 0.0f;
        #pragma unroll
        for (int w8 = 0; w8 < 8; w8++) c += cntp[w8][t];
        int mk = node_mask[b * NN + m0 + t];
        sm[t] = (float)mk / (c >= 0.5f ? c : 1.0f);
    }
    __syncthreads();

    // scale aggregate (linear => exact), then add self term on top
    #pragma unroll
    for (int fm = 0; fm < 2; fm++)
        #pragma unroll
        for (int r = 0; r < 4; r++) {
            float s = sm[fm * 16 + q * 4 + r];
            #pragma unroll
            for (int fd = 0; fd < 2; fd++) accO[fm][fd][r] *= s;
        }

    // ---- self: accO += node @ Ws^T
    #pragma unroll
    for (int ee = 0; ee < 8; ee++) {
        int e0c = ee * 32;
        bf16x8 afS[2], bwS[2];
        #pragma unroll
        for (int fm = 0; fm < 2; fm++)
            afS[fm] = *(const bf16x8*)(node_bf +
                ((size_t)(b * NN + m0 + fm * 16 + l16)) * DD + e0c + q * 8);
        #pragma unroll
        for (int fd = 0; fd < 2; fd++)
            bwS[fd] = *(const bf16x8*)(Ws_bf +
                ((size_t)(dsub + fd * 16 + l16)) * DD + e0c + q * 8);
        #pragma unroll
        for (int fm = 0; fm < 2; fm++)
            #pragma unroll
            for (int fd = 0; fd < 2; fd++)
                accO[fm][fd] = __builtin_amdgcn_mfma_f32_16x16x32_bf16(
                    afS[fm], bwS[fd], accO[fm][fd], 0, 0, 0);
    }

    // ---- epilogue: + bs, relu, store f32
    #pragma unroll
    for (int fm = 0; fm < 2; fm++)
        #pragma unroll
        for (int fd = 0; fd < 2; fd++) {
            int d = dsub + fd * 16 + l16;
            float bsv = bs[d];
            #pragma unroll
            for (int r = 0; r < 4; r++) {
                int m = m0 + fm * 16 + q * 4 + r;
                float v = accO[fm][fd][r] + bsv;
                out[((size_t)(b * NN + m)) * DD + d] = fmaxf(v, 0.0f);
            }
        }
#undef LOADG
#undef CONVERT
}

// ----------------------------------------------------------------
extern "C" void kernel_launch(void* const* d_in, const int* in_sizes, int n_in,
                              void* d_out, int out_size, void* d_ws, size_t ws_size,
                              hipStream_t stream) {
    const float* node      = (const float*)d_in[0];
    const float* Ww        = (const float*)d_in[1];
    const float* bw        = (const float*)d_in[2];
    const float* Ws        = (const float*)d_in[3];
    const float* bs        = (const float*)d_in[4];
    const float* Wk        = (const float*)d_in[5];
    const int*   node_mask = (const int*)d_in[6];
    const int*   graphs    = (const int*)d_in[7];
    float* out   = (float*)d_out;
    float* all_w = out + (size_t)BB * NN * DD;

    char* ws = (char*)d_ws;
    float*  wm      = (float*)(ws + WS_WM);
    __bf16* maskbf  = (__bf16*)(ws + WS_MASKBF);
    __bf16* node_bf = (__bf16*)(ws + WS_NODEBF);
    __bf16* node_t  = (__bf16*)(ws + WS_NODET);
    __bf16* Wk_bf   = (__bf16*)(ws + WS_WKBF);
    __bf16* Ws_bf   = (__bf16*)(ws + WS_WSBF);

    k1_prep    <<<2048, 256, 0, stream>>>(node, Ww, bw, node_mask, wm, maskbf, node_bf, all_w);
    k1b_convert<<< 832, 256, 0, stream>>>(Wk, Ws, Wk_bf, Ws_bf);
    k2_transpose<<<512, 256, 0, stream>>>(node, wm, node_t);
    k45_fused  <<< 256, 512, 0, stream>>>(graphs, node_mask, maskbf, node_t, node_bf,
                                          Wk_bf, Ws_bf, bs, out);
}

// Round 10
// 350.702 us; speedup vs baseline: 1.4327x; 1.3768x over previous
//
#include <hip/hip_runtime.h>
#include <hip/hip_bf16.h>
#include <math.h>

#define BB 16
#define NN 512
#define DD 256
#define KK 12

typedef __bf16 bf16x8 __attribute__((ext_vector_type(8)));
typedef __bf16 bf16x4 __attribute__((ext_vector_type(4)));
typedef float  f32x4  __attribute__((ext_vector_type(4)));

// workspace layout (bytes)
#define WS_WM     0              // wm[b,n] = w*mask_n, f32, 32KB
#define WS_MASKBF 32768          // maskbf[b,n] bf16 0/1, 16KB
#define WS_NODEBF 49152          // node bf16 [B][N][D] (unscaled, self term), 4MB
#define WS_NODET  4243456        // node_t bf16 [B][D][N], scaled by wm, 4MB
#define WS_WKBF   8437760        // Wk bf16 [K][D][D], 1.5MB
#define WS_WSBF   10010624       // Ws bf16 [D][D], 128KB

// raw barrier: drain LDS only; vmcnt deliberately NOT drained so global
// prefetch loads stay in flight across the barrier.
#define BAR() do { \
    __builtin_amdgcn_sched_barrier(0); \
    asm volatile("s_waitcnt lgkmcnt(0)" ::: "memory"); \
    __builtin_amdgcn_s_barrier(); \
    __builtin_amdgcn_sched_barrier(0); \
} while (0)

// ---------------------------------------------------------------- k1: w, all_weight, wm, maskbf, node_bf16
__global__ __launch_bounds__(256) void k1_prep(const float* __restrict__ node,
        const float* __restrict__ Ww, const float* __restrict__ bw,
        const int* __restrict__ node_mask,
        float* __restrict__ wm, __bf16* __restrict__ maskbf,
        __bf16* __restrict__ node_bf, float* __restrict__ all_w) {
    int t = threadIdx.x;
    int lane = t & 63;
    int row = blockIdx.x * 4 + (t >> 6);           // b*N + n
    const float4 nv = *(const float4*)(node + (size_t)row * DD + lane * 4);
    const float4 wv = *(const float4*)(Ww + lane * 4);
    float dot = nv.x*wv.x + nv.y*wv.y + nv.z*wv.z + nv.w*wv.w;
    #pragma unroll
    for (int off = 32; off > 0; off >>= 1) dot += __shfl_xor(dot, off);
    float w = 1.0f / (1.0f + expf(-(dot + bw[0])));
    int mk = node_mask[row];
    if (lane == 0) {
        wm[row]     = w * (float)mk;
        all_w[row]  = w;
        maskbf[row] = (__bf16)(float)mk;
    }
    bf16x4 nb = {(__bf16)nv.x, (__bf16)nv.y, (__bf16)nv.z, (__bf16)nv.w};
    *(bf16x4*)(node_bf + (size_t)row * DD + lane * 4) = nb;
}

// ---------------------------------------------------------------- k1b: Wk, Ws -> bf16
__global__ __launch_bounds__(256) void k1b_convert(const float* __restrict__ Wk,
        const float* __restrict__ Ws, __bf16* __restrict__ Wk_bf, __bf16* __restrict__ Ws_bf) {
    const int KDD = KK * DD * DD;
    int idx = (blockIdx.x * 256 + threadIdx.x) * 4;
    if (idx < KDD) {
        float4 v = *(const float4*)(Wk + idx);
        bf16x4 o = {(__bf16)v.x, (__bf16)v.y, (__bf16)v.z, (__bf16)v.w};
        *(bf16x4*)(Wk_bf + idx) = o;
    } else {
        int j = idx - KDD;
        if (j < DD * DD) {
            float4 v = *(const float4*)(Ws + j);
            bf16x4 o = {(__bf16)v.x, (__bf16)v.y, (__bf16)v.z, (__bf16)v.w};
            *(bf16x4*)(Ws_bf + j) = o;
        }
    }
}

// ---------------------------------------------------------------- k2: node fp32 [B][N][D] -> node_t bf16 [B][D][N] scaled by wm[b,n]
__global__ __launch_bounds__(256) void k2_transpose(const float* __restrict__ node,
        const float* __restrict__ wm, __bf16* __restrict__ dst) {
    __shared__ float tile[64][65];
    int bx = blockIdx.x;
    int b = bx >> 5; int rest = bx & 31; int nt = rest >> 2; int dt = rest & 3;
    int n0 = nt * 64, d0 = dt * 64;
    int t = threadIdx.x;
    #pragma unroll
    for (int i = 0; i < 16; i++) {
        int idx = i * 256 + t;
        int n = idx >> 6, d = idx & 63;
        tile[n][d] = node[((size_t)(b * NN + n0 + n)) * DD + d0 + d];
    }
    __syncthreads();
    #pragma unroll
    for (int i = 0; i < 16; i++) {
        int idx = i * 256 + t;
        int d = idx >> 6, n = idx & 63;
        float w = wm[b * NN + n0 + n];
        dst[((size_t)(b * DD + d0 + d)) * NN + n0 + n] = (__bf16)(tile[n][d] * w);
    }
}

// ---------------------------------------------------------------- k45: fused stageA+stageB
// Exactly the r4 schedule (dbuf Abf+Tk, one lgkm-only barrier per k, vmcnt
// floats) with the VGPR budget UNPINNED:
//  - __launch_bounds__(512, 1): hipcc's 2nd arg is CUDA-style min-blocks/CU
//    (r5/r9 evidence: (512,2)->cap 128, (512,4)->cap 64+spill). At our real
//    residency (1 block = 8 waves/CU) VGPR<=256 costs nothing.
//  - bfr (node_t fragments, k-INVARIANT) hoisted for kk=0..7 into 64 VGPRs:
//    those 8 L2-latency events per k vanish.
//  - kk=8..15 bfr batch-issued at stage-A top (16 loads in flight), draining
//    under the hoisted half's 32 MFMAs instead of serializing JIT.
__global__ __launch_bounds__(512, 1) void k45_fused(const int* __restrict__ graphs,
        const int* __restrict__ node_mask, const __bf16* __restrict__ maskbf,
        const __bf16* __restrict__ node_t, const __bf16* __restrict__ node_bf,
        const __bf16* __restrict__ Wk_bf, const __bf16* __restrict__ Ws_bf,
        const float* __restrict__ bs, float* __restrict__ out) {
    __shared__ __align__(16) __bf16 Abf[2][32][520]; // 66.6 KB adjacency dbuf
    __shared__ __align__(16) __bf16 Tk[2][32][264];  // 33.8 KB T-tile dbuf
    __shared__ float cntp[8][32];
    __shared__ float sm[32];
    int bx = blockIdx.x;
    int b  = (bx & 7) + 8 * ((bx >> 3) & 1);        // XCD-local b: each XCD sees b=x, x+8
    int mt = bx >> 4;
    int m0 = mt * 32;
    int t = threadIdx.x;
    int lane = t & 63;
    int w = t >> 6;                                  // wave 0..7
    int q = lane >> 4;
    int l16 = lane & 15;
    int esub = w * 32;                               // wave's e-range in stage A
    int dsub = w * 32;                               // wave's d-range in stage B

    int crow = t >> 7;                               // convert: row parity 0..3
    int ccol = (t & 127) * 4;                        // convert: int32-column base

    // ---- hoist: k-invariant node_t fragments for kk=0..7 (64 VGPRs)
    const __bf16* ntw = node_t + (size_t)(b * DD + esub) * NN;
    bf16x8 bfrh[8][2];
    #pragma unroll
    for (int kk = 0; kk < 8; kk++)
        #pragma unroll
        for (int fd = 0; fd < 2; fd++)
            bfrh[kk][fd] = *(const bf16x8*)(ntw +
                (size_t)(fd * 16 + l16) * NN + kk * 32 + q * 8);

    f32x4 accO[2][2];
    #pragma unroll
    for (int i = 0; i < 2; i++)
        #pragma unroll
        for (int j = 0; j < 2; j++) accO[i][j] = (f32x4){0.f, 0.f, 0.f, 0.f};
    f32x4 accC[2];
    accC[0] = (f32x4){0.f, 0.f, 0.f, 0.f};
    accC[1] = (f32x4){0.f, 0.f, 0.f, 0.f};

    int4 g[8];

#define LOADG(kk_) do { \
        const int4* gb = (const int4*)(graphs + ((size_t)(((kk_) * BB + b) * NN + m0)) * NN); \
        _Pragma("unroll") \
        for (int u = 0; u < 8; u++) g[u] = gb[u * 512 + t]; \
    } while (0)

#define CONVERT(nb_) do { \
        _Pragma("unroll") \
        for (int u = 0; u < 8; u++) { \
            int row = u * 4 + crow; \
            unsigned p0 = (unsigned)g[u].x | ((unsigned)g[u].y << 16); \
            unsigned p1 = (unsigned)g[u].z | ((unsigned)g[u].w << 16); \
            unsigned drel = (unsigned)(m0 + row - ccol); \
            if (drel < 2u)      p0 &= ~(0xFFFFu << (16 * drel)); \
            else if (drel < 4u) p1 &= ~(0xFFFFu << (16 * (drel - 2))); \
            uint2 st; st.x = p0 * 0x3F80u; st.y = p1 * 0x3F80u; \
            *(uint2*)&Abf[nb_][row][ccol] = st; \
        } \
    } while (0)

    // prologue: strip 0 -> regs -> Abf[0]; issue strip 1; barrier (Abf[0] ready)
    LOADG(0);
    CONVERT(0);
    LOADG(1);
    BAR();

    int ac = 0, tc = 0;

    #pragma unroll 1
    for (int k = 0; k < KK; k++) {
        // ---- stage A: T_k[m, e-sub] = sum_n A[m,n] * wnode[n,e], reading Abf[ac]
        f32x4 accT[2][2];
        #pragma unroll
        for (int i = 0; i < 2; i++)
            #pragma unroll
            for (int jj = 0; jj < 2; jj++) accT[i][jj] = (f32x4){0.f, 0.f, 0.f, 0.f};

        // batch-issue the streamed half (kk=8..15): 16 loads in flight,
        // draining under the hoisted half's MFMAs below
        bf16x8 bfrs[8][2];
        #pragma unroll
        for (int kk = 8; kk < 16; kk++)
            #pragma unroll
            for (int fd = 0; fd < 2; fd++)
                bfrs[kk - 8][fd] = *(const bf16x8*)(ntw +
                    (size_t)(fd * 16 + l16) * NN + kk * 32 + q * 8);

        // hoisted half: pure {LDS read + MFMA}
        #pragma unroll
        for (int kk = 0; kk < 8; kk++) {
            int n0c = kk * 32;
            bf16x8 af[2];
            #pragma unroll
            for (int fm = 0; fm < 2; fm++)
                af[fm] = *(const bf16x8*)&Abf[ac][fm * 16 + l16][n0c + q * 8];
            #pragma unroll
            for (int fm = 0; fm < 2; fm++)
                #pragma unroll
                for (int fd = 0; fd < 2; fd++)
                    accT[fm][fd] = __builtin_amdgcn_mfma_f32_16x16x32_bf16(
                        af[fm], bfrh[kk][fd], accT[fm][fd], 0, 0, 0);
            if ((kk >> 1) == w) {
                bf16x8 bfm = (bf16x8){0,0,0,0,0,0,0,0};
                if (l16 == 0)
                    bfm = *(const bf16x8*)(maskbf + b * NN + n0c + q * 8);
                accC[0] = __builtin_amdgcn_mfma_f32_16x16x32_bf16(af[0], bfm, accC[0], 0, 0, 0);
                accC[1] = __builtin_amdgcn_mfma_f32_16x16x32_bf16(af[1], bfm, accC[1], 0, 0, 0);
            }
        }

        // streamed half
        #pragma unroll
        for (int kk = 8; kk < 16; kk++) {
            int n0c = kk * 32;
            bf16x8 af[2];
            #pragma unroll
            for (int fm = 0; fm < 2; fm++)
                af[fm] = *(const bf16x8*)&Abf[ac][fm * 16 + l16][n0c + q * 8];
            #pragma unroll
            for (int fm = 0; fm < 2; fm++)
                #pragma unroll
                for (int fd = 0; fd < 2; fd++)
                    accT[fm][fd] = __builtin_amdgcn_mfma_f32_16x16x32_bf16(
                        af[fm], bfrs[kk - 8][fd], accT[fm][fd], 0, 0, 0);
            if ((kk >> 1) == w) {
                bf16x8 bfm = (bf16x8){0,0,0,0,0,0,0,0};
                if (l16 == 0)
                    bfm = *(const bf16x8*)(maskbf + b * NN + n0c + q * 8);
                accC[0] = __builtin_amdgcn_mfma_f32_16x16x32_bf16(af[0], bfm, accC[0], 0, 0, 0);
                accC[1] = __builtin_amdgcn_mfma_f32_16x16x32_bf16(af[1], bfm, accC[1], 0, 0, 0);
            }
        }

        // ---- convert strip k+1 into the other Abf buffer (overlaps stage A issue)
        if (k < KK - 1) CONVERT(ac ^ 1);
        // ---- issue strip k+2 loads; they stay in flight across the barrier
        if (k < KK - 2) LOADG(k + 2);

        // ---- T_k -> LDS bf16 (C/D layout: col=l16, row=q*4+r)
        #pragma unroll
        for (int fm = 0; fm < 2; fm++)
            #pragma unroll
            for (int fd = 0; fd < 2; fd++) {
                int col = esub + fd * 16 + l16;
                #pragma unroll
                for (int r = 0; r < 4; r++)
                    Tk[tc][fm * 16 + q * 4 + r][col] = (__bf16)accT[fm][fd][r];
            }

        BAR();                                       // Tk[tc] + Abf[ac^1] ready

        // ---- stage B: accO[m, d-sub] += sum_e T_k[m,e] * Wk[k,d,e]
        #pragma unroll
        for (int ee = 0; ee < 8; ee++) {
            int e0c = ee * 32;
            bf16x8 afT[2], bw2[2];
            #pragma unroll
            for (int fm = 0; fm < 2; fm++)
                afT[fm] = *(const bf16x8*)&Tk[tc][fm * 16 + l16][e0c + q * 8];
            #pragma unroll
            for (int fd = 0; fd < 2; fd++)
                bw2[fd] = *(const bf16x8*)(Wk_bf +
                    ((size_t)(k * DD + dsub + fd * 16 + l16)) * DD + e0c + q * 8);
            #pragma unroll
            for (int fm = 0; fm < 2; fm++)
                #pragma unroll
                for (int fd = 0; fd < 2; fd++)
                    accO[fm][fd] = __builtin_amdgcn_mfma_f32_16x16x32_bf16(
                        afT[fm], bw2[fd], accO[fm][fd], 0, 0, 0);
        }

        ac ^= 1; tc ^= 1;
    }

    // ---- counts: block-local reduce, s[m] = mask_m / max(1, cnt)
    if (l16 == 0) {
        #pragma unroll
        for (int fm = 0; fm < 2; fm++)
            #pragma unroll
            for (int r = 0; r < 4; r++)
                cntp[w][fm * 16 + q * 4 + r] = accC[fm][r];
    }
    __syncthreads();
    if (t < 32) {
        float c = 0.0f;
        #pragma unroll
        for (int w8 = 0; w8 < 8; w8++) c += cntp[w8][t];
        int mk = node_mask[b * NN + m0 + t];
        sm[t] = (float)mk / (c >= 0.5f ? c : 1.0f);
    }
    __syncthreads();

    // scale aggregate (linear => exact), then add self term on top
    #pragma unroll
    for (int fm = 0; fm < 2; fm++)
        #pragma unroll
        for (int r = 0; r < 4; r++) {
            float s = sm[fm * 16 + q * 4 + r];
            #pragma unroll
            for (int fd = 0; fd < 2; fd++) accO[fm][fd][r] *= s;
        }

    // ---- self: accO += node @ Ws^T
    #pragma unroll
    for (int ee = 0; ee < 8; ee++) {
        int e0c = ee * 32;
        bf16x8 afS[2], bwS[2];
        #pragma unroll
        for (int fm = 0; fm < 2; fm++)
            afS[fm] = *(const bf16x8*)(node_bf +
                ((size_t)(b * NN + m0 + fm * 16 + l16)) * DD + e0c + q * 8);
        #pragma unroll
        for (int fd = 0; fd < 2; fd++)
            bwS[fd] = *(const bf16x8*)(Ws_bf +
                ((size_t)(dsub + fd * 16 + l16)) * DD + e0c + q * 8);
        #pragma unroll
        for (int fm = 0; fm < 2; fm++)
            #pragma unroll
            for (int fd = 0; fd < 2; fd++)
                accO[fm][fd] = __builtin_amdgcn_mfma_f32_16x16x32_bf16(
                    afS[fm], bwS[fd], accO[fm][fd], 0, 0, 0);
    }

    // ---- epilogue: + bs, relu, store f32
    #pragma unroll
    for (int fm = 0; fm < 2; fm++)
        #pragma unroll
        for (int fd = 0; fd < 2; fd++) {
            int d = dsub + fd * 16 + l16;
            float bsv = bs[d];
            #pragma unroll
            for (int r = 0; r < 4; r++) {
                int m = m0 + fm * 16 + q * 4 + r;
                float v = accO[fm][fd][r] + bsv;
                out[((size_t)(b * NN + m)) * DD + d] = fmaxf(v, 0.0f);
            }
        }
#undef LOADG
#undef CONVERT
}

// ----------------------------------------------------------------
extern "C" void kernel_launch(void* const* d_in, const int* in_sizes, int n_in,
                              void* d_out, int out_size, void* d_ws, size_t ws_size,
                              hipStream_t stream) {
    const float* node      = (const float*)d_in[0];
    const float* Ww        = (const float*)d_in[1];
    const float* bw        = (const float*)d_in[2];
    const float* Ws        = (const float*)d_in[3];
    const float* bs        = (const float*)d_in[4];
    const float* Wk        = (const float*)d_in[5];
    const int*   node_mask = (const int*)d_in[6];
    const int*   graphs    = (const int*)d_in[7];
    float* out   = (float*)d_out;
    float* all_w = out + (size_t)BB * NN * DD;

    char* ws = (char*)d_ws;
    float*  wm      = (float*)(ws + WS_WM);
    __bf16* maskbf  = (__bf16*)(ws + WS_MASKBF);
    __bf16* node_bf = (__bf16*)(ws + WS_NODEBF);
    __bf16* node_t  = (__bf16*)(ws + WS_NODET);
    __bf16* Wk_bf   = (__bf16*)(ws + WS_WKBF);
    __bf16* Ws_bf   = (__bf16*)(ws + WS_WSBF);

    k1_prep    <<<2048, 256, 0, stream>>>(node, Ww, bw, node_mask, wm, maskbf, node_bf, all_w);
    k1b_convert<<< 832, 256, 0, stream>>>(Wk, Ws, Wk_bf, Ws_bf);
    k2_transpose<<<512, 256, 0, stream>>>(node, wm, node_t);
    k45_fused  <<< 256, 512, 0, stream>>>(graphs, node_mask, maskbf, node_t, node_bf,
                                          Wk_bf, Ws_bf, bs, out);
}